// Round 13
// baseline (148.434 us; speedup 1.0000x reference)
//
#include <hip/hip_runtime.h>
#include <math.h>

#define S_LEN 512
#define BATCH 16
#define DIN   512
#define DF    512
#define NMIX  10
#define NCHAR 1024
#define DCTX  256
#define M_ROWS (S_LEN*BATCH)   // 8192

// d_out layout (tuple flattened in return order)
#define OFF_CTXOUT 0
#define OFF_ATTN   (S_LEN*BATCH*DCTX)
#define OFF_MEANS  (OFF_ATTN + S_LEN*BATCH*NCHAR)
#define OFF_VARS   (OFF_MEANS + S_LEN*BATCH*NMIX)
#define OFF_WTS    (OFF_VARS  + S_LEN*BATCH*NMIX)

// scratch layout in d_ws (byte offsets)
#define WS_W1T   (8u<<20)     // f16  512 KB (512x512, [n][k] TRANSPOSED)
#define WS_W2T   (9u<<20)     // f32  64 KB  (32x512 padded)
#define WS_HH    (10u<<20)    // f16  8 MB
#define WS_ATTNH (26u<<20)    // f16  16.8 MB
#define WS_BOUND (44u<<20)    // u32  16     per-batch reach bound (float bits)

#define W1T_BLOCKS 64
#define W2T_BLOCKS 64

typedef float    f32x16 __attribute__((ext_vector_type(16)));
typedef float    f32x4v __attribute__((ext_vector_type(4)));
typedef _Float16 f16x8  __attribute__((ext_vector_type(8)));

__device__ __forceinline__ unsigned short f2h(float x) {
    union { _Float16 h; unsigned short u; } cv;
    cv.h = (_Float16)x;
    return cv.u;
}
__device__ __forceinline__ ushort4 cvt4(float4 v) {
    ushort4 o; o.x = f2h(v.x); o.y = f2h(v.y); o.z = f2h(v.z); o.w = f2h(v.w);
    return o;
}
__device__ __forceinline__ void nt_store4(float* p, float a, float b, float c, float d) {
    f32x4v v; v.x = a; v.y = b; v.z = c; v.w = d;
    __builtin_nontemporal_store(v, (f32x4v*)p);
}

// ---------------------------------------------------------------------------
// Kernel 0: W1 -> f16 TRANSPOSED [n][k]; W2^T fp32; zero bound[16].
// (X and ctx conversions folded into their consumers.)
// ---------------------------------------------------------------------------
__global__ __launch_bounds__(256) void convert_kernel(
    const float* __restrict__ W1, const float* __restrict__ W2,
    unsigned short* __restrict__ W1T, float* __restrict__ W2T,
    unsigned int* __restrict__ bound)
{
    const int bid = blockIdx.x;
    const int tid = threadIdx.x;
    if (bid < W1T_BLOCKS) {
        __shared__ unsigned short tile[64*68];
        const int k0 = (bid >> 3) * 64, n0 = (bid & 7) * 64;
        #pragma unroll
        for (int q = 0; q < 4; q++) {
            const int r = q*16 + (tid >> 4);
            const int c = (tid & 15) * 4;
            float4 v = *(const float4*)(W1 + (size_t)(k0+r)*DF + n0 + c);
            *(ushort4*)(tile + r*68 + c) = cvt4(v);
        }
        __syncthreads();
        #pragma unroll
        for (int q = 0; q < 4; q++) {
            const int n  = q*16 + (tid >> 4);
            const int kq = (tid & 15) * 4;
            ushort4 o;
            o.x = tile[(kq+0)*68 + n];
            o.y = tile[(kq+1)*68 + n];
            o.z = tile[(kq+2)*68 + n];
            o.w = tile[(kq+3)*68 + n];
            *(ushort4*)(W1T + (size_t)(n0+n)*DIN + k0 + kq) = o;
        }
    } else if (bid < W1T_BLOCKS + W2T_BLOCKS) {
        const int idx = (bid - W1T_BLOCKS)*256 + tid;
        if (idx < 512*32) {
            const int j = idx >> 9, k = idx & 511;
            W2T[idx] = (j < 30) ? W2[k*30 + j] : 0.f;
        }
    } else {
        if (tid < BATCH) bound[tid] = 0u;
    }
}

// ---------------------------------------------------------------------------
// Kernel 1: GEMM1 via f16 MFMA 32x32x16, 64x64 tiles.  A staged directly
// from f32 X (convert folded in, same pattern as ctx_mfma's B); B from
// pre-transposed f16 W1T.
// ---------------------------------------------------------------------------
__global__ __launch_bounds__(256) void gemm1_kernel(
    const float* __restrict__ X, const unsigned short* __restrict__ W1T,
    const float* __restrict__ b1, unsigned short* __restrict__ Hh)
{
    __shared__ __align__(16) unsigned short As[64*72];
    __shared__ __align__(16) unsigned short Bs[64*72];
    const int row0 = (blockIdx.x >> 3) * 64;
    const int n0   = (blockIdx.x & 7)  * 64;
    const int tid  = threadIdx.x;
    const int lane = tid & 63, w = tid >> 6;
    const int wr = (w >> 1) * 32, wc = (w & 1) * 32;
    const int m  = lane & 31,  g  = lane >> 5;
    const int sa = tid >> 2,   ka = (tid & 3) * 16;

    f32x16 acc = {};
    const float*          aptr = X   + (size_t)(row0+sa)*DIN + ka;
    const unsigned short* bptr = W1T + (size_t)(n0 +sa)*DIN + ka;

    for (int kt = 0; kt < DIN; kt += 64) {
        float4 af0 = *(const float4*)(aptr + kt);
        float4 af1 = *(const float4*)(aptr + kt + 4);
        float4 af2 = *(const float4*)(aptr + kt + 8);
        float4 af3 = *(const float4*)(aptr + kt + 12);
        uint4  bv0 = *(const uint4*)(bptr + kt);
        uint4  bv1 = *(const uint4*)(bptr + kt + 8);
        __syncthreads();
        {
            ushort4 h0 = cvt4(af0), h1 = cvt4(af1), h2 = cvt4(af2), h3 = cvt4(af3);
            *(ushort4*)(As + sa*72 + ka)      = h0;
            *(ushort4*)(As + sa*72 + ka + 4)  = h1;
            *(ushort4*)(As + sa*72 + ka + 8)  = h2;
            *(ushort4*)(As + sa*72 + ka + 12) = h3;
        }
        *(uint4*)(Bs + sa*72 + ka)     = bv0;
        *(uint4*)(Bs + sa*72 + ka + 8) = bv1;
        __syncthreads();
        #pragma unroll
        for (int ks = 0; ks < 64; ks += 16) {
            f16x8 af = *(const f16x8*)(As + (wr+m)*72 + ks + g*8);
            f16x8 bf = *(const f16x8*)(Bs + (wc+m)*72 + ks + g*8);
            acc = __builtin_amdgcn_mfma_f32_32x32x16_f16(af, bf, acc, 0, 0, 0);
        }
    }
    const int ncol = n0 + wc + m;
    const float bb = b1[ncol];
    #pragma unroll
    for (int r = 0; r < 16; r++) {
        const int rowloc = (r & 3) + 8*(r >> 2) + 4*g;
        const int row = row0 + wr + rowloc;
        float v = acc[r] + bb;
        v = v > 0.f ? v : 0.01f * v;
        Hh[(size_t)row*DF + ncol] = f2h(v);
    }
}

// ---------------------------------------------------------------------------
// Kernel 2: GEMM2 (8192x30, K=512); LDS-staged H, broadcast W2T reads.
// ---------------------------------------------------------------------------
__global__ __launch_bounds__(256) void gemm2_kernel(
    const unsigned short* __restrict__ Hh, const float* __restrict__ W2T,
    const float* __restrict__ b2,
    float* __restrict__ dmeans, float* __restrict__ dvars, float* __restrict__ dwts)
{
    __shared__ __align__(16) unsigned short Hs[32*520];
    const int tid = threadIdx.x;
    const int r0  = blockIdx.x * 32;
    {
        const uint4* src = (const uint4*)(Hh + (size_t)r0*DF);
        #pragma unroll
        for (int i = 0; i < 8; i++) {
            int u   = tid + i*256;
            int row = u >> 6;
            int col = (u & 63) * 8;
            *(uint4*)(Hs + row*520 + col) = src[u];
        }
    }
    __syncthreads();

    const int r  = tid & 31;
    const int j0 = tid >> 5;
    const unsigned short* hrow = Hs + r*520;
    float acc[4] = {0.f, 0.f, 0.f, 0.f};

    for (int k0 = 0; k0 < DF; k0 += 8) {
        union { uint4 u; _Float16 h[8]; } hv;
        hv.u = *(const uint4*)(hrow + k0);
        float wv[4][8];
        #pragma unroll
        for (int q = 0; q < 4; q++) {
            *(float4*)(wv[q])     = *(const float4*)(W2T + (size_t)(j0 + q*8)*DF + k0);
            *(float4*)(wv[q] + 4) = *(const float4*)(W2T + (size_t)(j0 + q*8)*DF + k0 + 4);
        }
        #pragma unroll
        for (int i = 0; i < 8; i++) {
            float hf = (float)hv.h[i];
            acc[0] = fmaf(hf, wv[0][i], acc[0]);
            acc[1] = fmaf(hf, wv[1][i], acc[1]);
            acc[2] = fmaf(hf, wv[2][i], acc[2]);
            acc[3] = fmaf(hf, wv[3][i], acc[3]);
        }
    }
    const int row = r0 + r;
    #pragma unroll
    for (int q = 0; q < 4; q++) {
        const int j = j0 + q*8;
        if (j >= 30) continue;
        float dot = acc[q] + b2[j];
        float sp  = fmaxf(dot, 0.f) + log1pf(__expf(-fabsf(dot)));
        if (j < 10)       dmeans[row*NMIX + j]      = sp / 25.0f;
        else if (j < 20)  dvars [row*NMIX + (j-10)] = fminf(fmaxf(sp, 0.01f), 100.f);
        else              dwts  [row*NMIX + (j-20)] = sp;
    }
}

// ---------------------------------------------------------------------------
// Kernel 3: scan (in-place on means region) + per-batch reach bound.
// ---------------------------------------------------------------------------
__global__ __launch_bounds__(512) void scan_kernel(
    const float* __restrict__ init_means, float* __restrict__ means,
    const float* __restrict__ vars_g, unsigned int* __restrict__ bound)
{
    const int p    = blockIdx.x;
    const int s    = threadIdx.x;
    const int lane = s & 63;
    const int wid  = s >> 6;

    float x = means[s*(BATCH*NMIX) + p];
    #pragma unroll
    for (int d = 1; d < 64; d <<= 1) {
        float tv = __shfl_up(x, d, 64);
        if (lane >= d) x += tv;
    }
    __shared__ float wsum[8];
    __shared__ float wmax[8];
    if (lane == 63) wsum[wid] = x;
    __syncthreads();
    float off = init_means[p];
    for (int i = 0; i < wid; i++) off += wsum[i];
    x += off;
    means[s*(BATCH*NMIX) + p] = x;

    float v = vars_g[s*(BATCH*NMIX) + p];
    float reach = x + 4.8f * rsqrtf(v);
    #pragma unroll
    for (int d = 32; d >= 1; d >>= 1)
        reach = fmaxf(reach, __shfl_xor(reach, d, 64));
    if (lane == 0) wmax[wid] = reach;
    __syncthreads();
    if (s == 0) {
        float mx = wmax[0];
        #pragma unroll
        for (int i = 1; i < 8; i++) mx = fmaxf(mx, wmax[i]);
        atomicMax((int*)&bound[p / NMIX], __float_as_int(mx));
    }
}

// ---------------------------------------------------------------------------
// Kernel 4: attention weights.  Zero fast-path beyond per-batch bound;
// f32 output via non-temporal stores; attnh only t < kmax.
// ---------------------------------------------------------------------------
__global__ __launch_bounds__(256) void attn_kernel(
    const float* __restrict__ means, const float* __restrict__ vars,
    const float* __restrict__ wts,   const unsigned int* __restrict__ bound,
    float* __restrict__ attn, unsigned short* __restrict__ attnh)
{
    const int row = blockIdx.x;
    const int b   = row & (BATCH-1);
    const int tid = threadIdx.x;
    const int bd  = (int)__int_as_float((int)bound[b]);
    const int kmax = min(NCHAR, (bd + 64) & ~63);
    const int t0  = tid * 4;

    float o[4] = {0.f, 0.f, 0.f, 0.f};
    if (t0 <= bd) {
        float m[NMIX], v[NMIX], w[NMIX];
        #pragma unroll
        for (int k = 0; k < NMIX; k++) {
            m[k] = means[row*NMIX + k];
            v[k] = vars [row*NMIX + k];
            w[k] = wts  [row*NMIX + k];
        }
        #pragma unroll
        for (int i = 0; i < 4; i++) {
            const float t = (float)(t0 + i);
            float sum = 0.f;
            #pragma unroll
            for (int k = 0; k < NMIX; k++) {
                float d = t - m[k];
                sum += w[k] * __expf(-d*d*v[k]);
            }
            o[i] = sum;
        }
    }
    nt_store4(attn + (size_t)row*NCHAR + t0, o[0], o[1], o[2], o[3]);
    if (t0 < kmax) {
        ushort4 h; h.x = f2h(o[0]); h.y = f2h(o[1]); h.z = f2h(o[2]); h.w = f2h(o[3]);
        *(ushort4*)(attnh + (size_t)row*NCHAR + t0) = h;
    }
}

// ---------------------------------------------------------------------------
// Kernel 5: attended contexts via f16 MFMA; K-loop clipped to kmax[b];
// B staged directly from f32 ctx; nt epilogue stores.
// ---------------------------------------------------------------------------
__global__ __launch_bounds__(256) void ctx_mfma_kernel(
    const unsigned short* __restrict__ attnh, const float* __restrict__ ctx,
    const unsigned int* __restrict__ bound, float* __restrict__ out)
{
    __shared__ __align__(16) unsigned short As[64*72];
    __shared__ __align__(16) unsigned short Bs[64*72];
    const int bid  = blockIdx.x;
    const int b    = bid >> 5;
    const int rem  = bid & 31;
    const int s0   = (rem >> 2) * 64;
    const int d0   = (rem & 3)  * 64;
    const int tid  = threadIdx.x;
    const int lane = tid & 63, w = tid >> 6;
    const int wr = (w >> 1) * 32, wc = (w & 1) * 32;
    const int m  = lane & 31,  g  = lane >> 5;
    const int sl = tid >> 2,   tq = (tid & 3) * 16;
    const int tb = tid & 63,   db = (tid >> 6) * 16;

    const int bd   = (int)__int_as_float((int)bound[b]);
    const int kmax = min(NCHAR, (bd + 64) & ~63);

    f32x16 acc = {};
    const unsigned short* abase = attnh + (size_t)(s0+sl)*(BATCH*NCHAR) + b*NCHAR + tq;
    const float*          bbase = ctx   + (size_t)b*DCTX + d0 + db;

    for (int kt = 0; kt < kmax; kt += 64) {
        uint4 a0  = *(const uint4*)(abase + kt);
        uint4 a1  = *(const uint4*)(abase + kt + 8);
        float4 bf0 = *(const float4*)(bbase + (size_t)(kt+tb)*(BATCH*DCTX));
        float4 bf1 = *(const float4*)(bbase + (size_t)(kt+tb)*(BATCH*DCTX) + 4);
        float4 bf2 = *(const float4*)(bbase + (size_t)(kt+tb)*(BATCH*DCTX) + 8);
        float4 bf3 = *(const float4*)(bbase + (size_t)(kt+tb)*(BATCH*DCTX) + 12);
        __syncthreads();
        *(uint4*)(As + sl*72 + tq)     = a0;
        *(uint4*)(As + sl*72 + tq + 8) = a1;
        {
            ushort4 h0 = cvt4(bf0), h1 = cvt4(bf1), h2 = cvt4(bf2), h3 = cvt4(bf3);
            Bs[(db + 0)*72 + tb] = h0.x;  Bs[(db + 1)*72 + tb] = h0.y;
            Bs[(db + 2)*72 + tb] = h0.z;  Bs[(db + 3)*72 + tb] = h0.w;
            Bs[(db + 4)*72 + tb] = h1.x;  Bs[(db + 5)*72 + tb] = h1.y;
            Bs[(db + 6)*72 + tb] = h1.z;  Bs[(db + 7)*72 + tb] = h1.w;
            Bs[(db + 8)*72 + tb] = h2.x;  Bs[(db + 9)*72 + tb] = h2.y;
            Bs[(db +10)*72 + tb] = h2.z;  Bs[(db +11)*72 + tb] = h2.w;
            Bs[(db +12)*72 + tb] = h3.x;  Bs[(db +13)*72 + tb] = h3.y;
            Bs[(db +14)*72 + tb] = h3.z;  Bs[(db +15)*72 + tb] = h3.w;
        }
        __syncthreads();
        #pragma unroll
        for (int ks = 0; ks < 64; ks += 16) {
            f16x8 af = *(const f16x8*)(As + (wr+m)*72 + ks + g*8);
            f16x8 bf = *(const f16x8*)(Bs + (wc+m)*72 + ks + g*8);
            acc = __builtin_amdgcn_mfma_f32_32x32x16_f16(af, bf, acc, 0, 0, 0);
        }
    }
    #pragma unroll
    for (int r = 0; r < 16; r++) {
        int rowloc = (r & 3) + 8*(r >> 2) + 4*g;
        int s = s0 + wr + rowloc;
        __builtin_nontemporal_store(acc[r],
            out + (size_t)s*(BATCH*DCTX) + b*DCTX + d0 + wc + m);
    }
}

// ---------------------------------------------------------------------------
extern "C" void kernel_launch(void* const* d_in, const int* in_sizes, int n_in,
                              void* d_out, int out_size, void* d_ws, size_t ws_size,
                              hipStream_t stream)
{
    const float* X     = (const float*)d_in[0];
    const float* ctx   = (const float*)d_in[1];
    const float* initm = (const float*)d_in[2];
    const float* W1    = (const float*)d_in[3];
    const float* b1    = (const float*)d_in[4];
    const float* W2    = (const float*)d_in[5];
    const float* b2    = (const float*)d_in[6];

    float* out      = (float*)d_out;
    float* out_ctx  = out + OFF_CTXOUT;
    float* out_attn = out + OFF_ATTN;
    float* out_mean = out + OFF_MEANS;
    float* out_var  = out + OFF_VARS;
    float* out_wts  = out + OFF_WTS;

    char* ws = (char*)d_ws;
    unsigned short* W1T   = (unsigned short*)(ws + WS_W1T);
    float*          W2T   = (float*)         (ws + WS_W2T);
    unsigned short* Hh    = (unsigned short*)(ws + WS_HH);
    unsigned short* attnh = (unsigned short*)(ws + WS_ATTNH);
    unsigned int*   bnd   = (unsigned int*)  (ws + WS_BOUND);

    convert_kernel<<<W1T_BLOCKS + W2T_BLOCKS + 1, 256, 0, stream>>>(
        W1, W2, W1T, W2T, bnd);
    gemm1_kernel<<<(M_ROWS/64)*(DF/64), 256, 0, stream>>>(X, W1T, b1, Hh);
    gemm2_kernel<<<M_ROWS/32, 256, 0, stream>>>(Hh, W2T, b2, out_mean, out_var, out_wts);
    scan_kernel<<<BATCH*NMIX, 512, 0, stream>>>(initm, out_mean, out_var, bnd);
    attn_kernel<<<M_ROWS, 256, 0, stream>>>(out_mean, out_var, out_wts, bnd,
                                            out_attn, attnh);
    ctx_mfma_kernel<<<16*8*4, 256, 0, stream>>>(attnh, ctx, bnd, out_ctx);
}

// Round 14
// 143.831 us; speedup vs baseline: 1.0320x; 1.0320x over previous
//
#include <hip/hip_runtime.h>
#include <math.h>

#define S_LEN 512
#define BATCH 16
#define DIN   512
#define DF    512
#define NMIX  10
#define NCHAR 1024
#define DCTX  256
#define M_ROWS (S_LEN*BATCH)   // 8192

// d_out layout (tuple flattened in return order)
#define OFF_CTXOUT 0
#define OFF_ATTN   (S_LEN*BATCH*DCTX)
#define OFF_MEANS  (OFF_ATTN + S_LEN*BATCH*NCHAR)
#define OFF_VARS   (OFF_MEANS + S_LEN*BATCH*NMIX)
#define OFF_WTS    (OFF_VARS  + S_LEN*BATCH*NMIX)

// scratch layout in d_ws (byte offsets)
#define WS_XH    0            // f16  8 MB   (8192x512)
#define WS_W1T   (8u<<20)     // f16  512 KB (512x512, [n][k] TRANSPOSED)
#define WS_W2T   (9u<<20)     // f32  64 KB  (32x512 padded)
#define WS_HH    (10u<<20)    // f16  8 MB
#define WS_ATTNH (26u<<20)    // f16  16.8 MB
#define WS_BOUND (44u<<20)    // u32  16     per-batch reach bound (float bits)

#define NX4     1048576       // X float4 count
#define CVT_BLOCKS (NX4/256)  // 4096
#define W1T_BLOCKS 64
#define W2T_BLOCKS 64

typedef float    f32x16 __attribute__((ext_vector_type(16)));
typedef float    f32x4v __attribute__((ext_vector_type(4)));
typedef _Float16 f16x8  __attribute__((ext_vector_type(8)));

__device__ __forceinline__ unsigned short f2h(float x) {
    union { _Float16 h; unsigned short u; } cv;
    cv.h = (_Float16)x;
    return cv.u;
}
__device__ __forceinline__ ushort4 cvt4(float4 v) {
    ushort4 o; o.x = f2h(v.x); o.y = f2h(v.y); o.z = f2h(v.z); o.w = f2h(v.w);
    return o;
}
__device__ __forceinline__ void nt_store4(float* p, float a, float b, float c, float d) {
    f32x4v v; v.x = a; v.y = b; v.z = c; v.w = d;
    __builtin_nontemporal_store(v, (f32x4v*)p);
}

// ---------------------------------------------------------------------------
// Kernel 0: convert X -> f16; W1 -> f16 TRANSPOSED [n][k]; W2^T fp32;
// zero bound[16].  (ctx conversion folded into ctx_mfma_kernel — it reads
// each element at full parallelism; X conversion stays standalone because
// gemm1 re-reads each X row 8x and f16 halves that traffic.)
// ---------------------------------------------------------------------------
__global__ __launch_bounds__(256) void convert_kernel(
    const float* __restrict__ X, const float* __restrict__ W1,
    const float* __restrict__ W2,
    unsigned short* __restrict__ Xh, unsigned short* __restrict__ W1T,
    float* __restrict__ W2T, unsigned int* __restrict__ bound)
{
    const int bid = blockIdx.x;
    const int tid = threadIdx.x;
    if (bid < CVT_BLOCKS) {
        const int i4 = bid*256 + tid;
        ((ushort4*)Xh)[i4] = cvt4(((const float4*)X)[i4]);
    } else if (bid < CVT_BLOCKS + W1T_BLOCKS) {
        __shared__ unsigned short tile[64*68];
        const int b2 = bid - CVT_BLOCKS;
        const int k0 = (b2 >> 3) * 64, n0 = (b2 & 7) * 64;
        #pragma unroll
        for (int q = 0; q < 4; q++) {
            const int r = q*16 + (tid >> 4);
            const int c = (tid & 15) * 4;
            float4 v = *(const float4*)(W1 + (size_t)(k0+r)*DF + n0 + c);
            *(ushort4*)(tile + r*68 + c) = cvt4(v);
        }
        __syncthreads();
        #pragma unroll
        for (int q = 0; q < 4; q++) {
            const int n  = q*16 + (tid >> 4);
            const int kq = (tid & 15) * 4;
            ushort4 o;
            o.x = tile[(kq+0)*68 + n];
            o.y = tile[(kq+1)*68 + n];
            o.z = tile[(kq+2)*68 + n];
            o.w = tile[(kq+3)*68 + n];
            *(ushort4*)(W1T + (size_t)(n0+n)*DIN + k0 + kq) = o;
        }
    } else if (bid < CVT_BLOCKS + W1T_BLOCKS + W2T_BLOCKS) {
        const int idx = (bid - CVT_BLOCKS - W1T_BLOCKS)*256 + tid;
        if (idx < 512*32) {
            const int j = idx >> 9, k = idx & 511;
            W2T[idx] = (j < 30) ? W2[k*30 + j] : 0.f;
        }
    } else {
        if (tid < BATCH) bound[tid] = 0u;
    }
}

// ---------------------------------------------------------------------------
// Kernel 1: GEMM1 via f16 MFMA 32x32x16, 64x64 tiles, k-major operands.
// ---------------------------------------------------------------------------
__global__ __launch_bounds__(256) void gemm1_kernel(
    const unsigned short* __restrict__ Xh, const unsigned short* __restrict__ W1T,
    const float* __restrict__ b1, unsigned short* __restrict__ Hh)
{
    __shared__ __align__(16) unsigned short As[64*72];
    __shared__ __align__(16) unsigned short Bs[64*72];
    const int row0 = (blockIdx.x >> 3) * 64;
    const int n0   = (blockIdx.x & 7)  * 64;
    const int tid  = threadIdx.x;
    const int lane = tid & 63, w = tid >> 6;
    const int wr = (w >> 1) * 32, wc = (w & 1) * 32;
    const int m  = lane & 31,  g  = lane >> 5;
    const int sa = tid >> 2,   ka = (tid & 3) * 16;

    f32x16 acc = {};
    const unsigned short* aptr = Xh  + (size_t)(row0+sa)*DIN + ka;
    const unsigned short* bptr = W1T + (size_t)(n0 +sa)*DIN + ka;

    for (int kt = 0; kt < DIN; kt += 64) {
        uint4 av0 = *(const uint4*)(aptr + kt);
        uint4 av1 = *(const uint4*)(aptr + kt + 8);
        uint4 bv0 = *(const uint4*)(bptr + kt);
        uint4 bv1 = *(const uint4*)(bptr + kt + 8);
        __syncthreads();
        *(uint4*)(As + sa*72 + ka)     = av0;
        *(uint4*)(As + sa*72 + ka + 8) = av1;
        *(uint4*)(Bs + sa*72 + ka)     = bv0;
        *(uint4*)(Bs + sa*72 + ka + 8) = bv1;
        __syncthreads();
        #pragma unroll
        for (int ks = 0; ks < 64; ks += 16) {
            f16x8 af = *(const f16x8*)(As + (wr+m)*72 + ks + g*8);
            f16x8 bf = *(const f16x8*)(Bs + (wc+m)*72 + ks + g*8);
            acc = __builtin_amdgcn_mfma_f32_32x32x16_f16(af, bf, acc, 0, 0, 0);
        }
    }
    const int ncol = n0 + wc + m;
    const float bb = b1[ncol];
    #pragma unroll
    for (int r = 0; r < 16; r++) {
        const int rowloc = (r & 3) + 8*(r >> 2) + 4*g;
        const int row = row0 + wr + rowloc;
        float v = acc[r] + bb;
        v = v > 0.f ? v : 0.01f * v;
        Hh[(size_t)row*DF + ncol] = f2h(v);
    }
}

// ---------------------------------------------------------------------------
// Kernel 2: GEMM2 (8192x30, K=512); LDS-staged H, broadcast W2T reads.
// ---------------------------------------------------------------------------
__global__ __launch_bounds__(256) void gemm2_kernel(
    const unsigned short* __restrict__ Hh, const float* __restrict__ W2T,
    const float* __restrict__ b2,
    float* __restrict__ dmeans, float* __restrict__ dvars, float* __restrict__ dwts)
{
    __shared__ __align__(16) unsigned short Hs[32*520];
    const int tid = threadIdx.x;
    const int r0  = blockIdx.x * 32;
    {
        const uint4* src = (const uint4*)(Hh + (size_t)r0*DF);
        #pragma unroll
        for (int i = 0; i < 8; i++) {
            int u   = tid + i*256;
            int row = u >> 6;
            int col = (u & 63) * 8;
            *(uint4*)(Hs + row*520 + col) = src[u];
        }
    }
    __syncthreads();

    const int r  = tid & 31;
    const int j0 = tid >> 5;
    const unsigned short* hrow = Hs + r*520;
    float acc[4] = {0.f, 0.f, 0.f, 0.f};

    for (int k0 = 0; k0 < DF; k0 += 8) {
        union { uint4 u; _Float16 h[8]; } hv;
        hv.u = *(const uint4*)(hrow + k0);
        float wv[4][8];
        #pragma unroll
        for (int q = 0; q < 4; q++) {
            *(float4*)(wv[q])     = *(const float4*)(W2T + (size_t)(j0 + q*8)*DF + k0);
            *(float4*)(wv[q] + 4) = *(const float4*)(W2T + (size_t)(j0 + q*8)*DF + k0 + 4);
        }
        #pragma unroll
        for (int i = 0; i < 8; i++) {
            float hf = (float)hv.h[i];
            acc[0] = fmaf(hf, wv[0][i], acc[0]);
            acc[1] = fmaf(hf, wv[1][i], acc[1]);
            acc[2] = fmaf(hf, wv[2][i], acc[2]);
            acc[3] = fmaf(hf, wv[3][i], acc[3]);
        }
    }
    const int row = r0 + r;
    #pragma unroll
    for (int q = 0; q < 4; q++) {
        const int j = j0 + q*8;
        if (j >= 30) continue;
        float dot = acc[q] + b2[j];
        float sp  = fmaxf(dot, 0.f) + log1pf(__expf(-fabsf(dot)));
        if (j < 10)       dmeans[row*NMIX + j]      = sp / 25.0f;
        else if (j < 20)  dvars [row*NMIX + (j-10)] = fminf(fmaxf(sp, 0.01f), 100.f);
        else              dwts  [row*NMIX + (j-20)] = sp;
    }
}

// ---------------------------------------------------------------------------
// Kernel 3: scan (in-place on means region) + per-batch reach bound.
// ---------------------------------------------------------------------------
__global__ __launch_bounds__(512) void scan_kernel(
    const float* __restrict__ init_means, float* __restrict__ means,
    const float* __restrict__ vars_g, unsigned int* __restrict__ bound)
{
    const int p    = blockIdx.x;
    const int s    = threadIdx.x;
    const int lane = s & 63;
    const int wid  = s >> 6;

    float x = means[s*(BATCH*NMIX) + p];
    #pragma unroll
    for (int d = 1; d < 64; d <<= 1) {
        float tv = __shfl_up(x, d, 64);
        if (lane >= d) x += tv;
    }
    __shared__ float wsum[8];
    __shared__ float wmax[8];
    if (lane == 63) wsum[wid] = x;
    __syncthreads();
    float off = init_means[p];
    for (int i = 0; i < wid; i++) off += wsum[i];
    x += off;
    means[s*(BATCH*NMIX) + p] = x;

    float v = vars_g[s*(BATCH*NMIX) + p];
    float reach = x + 4.8f * rsqrtf(v);
    #pragma unroll
    for (int d = 32; d >= 1; d >>= 1)
        reach = fmaxf(reach, __shfl_xor(reach, d, 64));
    if (lane == 0) wmax[wid] = reach;
    __syncthreads();
    if (s == 0) {
        float mx = wmax[0];
        #pragma unroll
        for (int i = 1; i < 8; i++) mx = fmaxf(mx, wmax[i]);
        atomicMax((int*)&bound[p / NMIX], __float_as_int(mx));
    }
}

// ---------------------------------------------------------------------------
// Kernel 4: attention weights.  Zero fast-path beyond per-batch bound;
// f32 output via non-temporal stores; attnh only t < kmax.
// ---------------------------------------------------------------------------
__global__ __launch_bounds__(256) void attn_kernel(
    const float* __restrict__ means, const float* __restrict__ vars,
    const float* __restrict__ wts,   const unsigned int* __restrict__ bound,
    float* __restrict__ attn, unsigned short* __restrict__ attnh)
{
    const int row = blockIdx.x;
    const int b   = row & (BATCH-1);
    const int tid = threadIdx.x;
    const int bd  = (int)__int_as_float((int)bound[b]);
    const int kmax = min(NCHAR, (bd + 64) & ~63);
    const int t0  = tid * 4;

    float o[4] = {0.f, 0.f, 0.f, 0.f};
    if (t0 <= bd) {
        float m[NMIX], v[NMIX], w[NMIX];
        #pragma unroll
        for (int k = 0; k < NMIX; k++) {
            m[k] = means[row*NMIX + k];
            v[k] = vars [row*NMIX + k];
            w[k] = wts  [row*NMIX + k];
        }
        #pragma unroll
        for (int i = 0; i < 4; i++) {
            const float t = (float)(t0 + i);
            float sum = 0.f;
            #pragma unroll
            for (int k = 0; k < NMIX; k++) {
                float d = t - m[k];
                sum += w[k] * __expf(-d*d*v[k]);
            }
            o[i] = sum;
        }
    }
    nt_store4(attn + (size_t)row*NCHAR + t0, o[0], o[1], o[2], o[3]);
    if (t0 < kmax) {
        ushort4 h; h.x = f2h(o[0]); h.y = f2h(o[1]); h.z = f2h(o[2]); h.w = f2h(o[3]);
        *(ushort4*)(attnh + (size_t)row*NCHAR + t0) = h;
    }
}

// ---------------------------------------------------------------------------
// Kernel 5: attended contexts via f16 MFMA; K-loop clipped to kmax[b];
// B staged directly from f32 ctx; nt epilogue stores.
// ---------------------------------------------------------------------------
__global__ __launch_bounds__(256) void ctx_mfma_kernel(
    const unsigned short* __restrict__ attnh, const float* __restrict__ ctx,
    const unsigned int* __restrict__ bound, float* __restrict__ out)
{
    __shared__ __align__(16) unsigned short As[64*72];
    __shared__ __align__(16) unsigned short Bs[64*72];
    const int bid  = blockIdx.x;
    const int b    = bid >> 5;
    const int rem  = bid & 31;
    const int s0   = (rem >> 2) * 64;
    const int d0   = (rem & 3)  * 64;
    const int tid  = threadIdx.x;
    const int lane = tid & 63, w = tid >> 6;
    const int wr = (w >> 1) * 32, wc = (w & 1) * 32;
    const int m  = lane & 31,  g  = lane >> 5;
    const int sl = tid >> 2,   tq = (tid & 3) * 16;
    const int tb = tid & 63,   db = (tid >> 6) * 16;

    const int bd   = (int)__int_as_float((int)bound[b]);
    const int kmax = min(NCHAR, (bd + 64) & ~63);

    f32x16 acc = {};
    const unsigned short* abase = attnh + (size_t)(s0+sl)*(BATCH*NCHAR) + b*NCHAR + tq;
    const float*          bbase = ctx   + (size_t)b*DCTX + d0 + db;

    for (int kt = 0; kt < kmax; kt += 64) {
        uint4 a0  = *(const uint4*)(abase + kt);
        uint4 a1  = *(const uint4*)(abase + kt + 8);
        float4 bf0 = *(const float4*)(bbase + (size_t)(kt+tb)*(BATCH*DCTX));
        float4 bf1 = *(const float4*)(bbase + (size_t)(kt+tb)*(BATCH*DCTX) + 4);
        float4 bf2 = *(const float4*)(bbase + (size_t)(kt+tb)*(BATCH*DCTX) + 8);
        float4 bf3 = *(const float4*)(bbase + (size_t)(kt+tb)*(BATCH*DCTX) + 12);
        __syncthreads();
        *(uint4*)(As + sl*72 + tq)     = a0;
        *(uint4*)(As + sl*72 + tq + 8) = a1;
        {
            ushort4 h0 = cvt4(bf0), h1 = cvt4(bf1), h2 = cvt4(bf2), h3 = cvt4(bf3);
            Bs[(db + 0)*72 + tb] = h0.x;  Bs[(db + 1)*72 + tb] = h0.y;
            Bs[(db + 2)*72 + tb] = h0.z;  Bs[(db + 3)*72 + tb] = h0.w;
            Bs[(db + 4)*72 + tb] = h1.x;  Bs[(db + 5)*72 + tb] = h1.y;
            Bs[(db + 6)*72 + tb] = h1.z;  Bs[(db + 7)*72 + tb] = h1.w;
            Bs[(db + 8)*72 + tb] = h2.x;  Bs[(db + 9)*72 + tb] = h2.y;
            Bs[(db +10)*72 + tb] = h2.z;  Bs[(db +11)*72 + tb] = h2.w;
            Bs[(db +12)*72 + tb] = h3.x;  Bs[(db +13)*72 + tb] = h3.y;
            Bs[(db +14)*72 + tb] = h3.z;  Bs[(db +15)*72 + tb] = h3.w;
        }
        __syncthreads();
        #pragma unroll
        for (int ks = 0; ks < 64; ks += 16) {
            f16x8 af = *(const f16x8*)(As + (wr+m)*72 + ks + g*8);
            f16x8 bf = *(const f16x8*)(Bs + (wc+m)*72 + ks + g*8);
            acc = __builtin_amdgcn_mfma_f32_32x32x16_f16(af, bf, acc, 0, 0, 0);
        }
    }
    #pragma unroll
    for (int r = 0; r < 16; r++) {
        int rowloc = (r & 3) + 8*(r >> 2) + 4*g;
        int s = s0 + wr + rowloc;
        __builtin_nontemporal_store(acc[r],
            out + (size_t)s*(BATCH*DCTX) + b*DCTX + d0 + wc + m);
    }
}

// ---------------------------------------------------------------------------
extern "C" void kernel_launch(void* const* d_in, const int* in_sizes, int n_in,
                              void* d_out, int out_size, void* d_ws, size_t ws_size,
                              hipStream_t stream)
{
    const float* X     = (const float*)d_in[0];
    const float* ctx   = (const float*)d_in[1];
    const float* initm = (const float*)d_in[2];
    const float* W1    = (const float*)d_in[3];
    const float* b1    = (const float*)d_in[4];
    const float* W2    = (const float*)d_in[5];
    const float* b2    = (const float*)d_in[6];

    float* out      = (float*)d_out;
    float* out_ctx  = out + OFF_CTXOUT;
    float* out_attn = out + OFF_ATTN;
    float* out_mean = out + OFF_MEANS;
    float* out_var  = out + OFF_VARS;
    float* out_wts  = out + OFF_WTS;

    char* ws = (char*)d_ws;
    unsigned short* Xh    = (unsigned short*)(ws + WS_XH);
    unsigned short* W1T   = (unsigned short*)(ws + WS_W1T);
    float*          W2T   = (float*)         (ws + WS_W2T);
    unsigned short* Hh    = (unsigned short*)(ws + WS_HH);
    unsigned short* attnh = (unsigned short*)(ws + WS_ATTNH);
    unsigned int*   bnd   = (unsigned int*)  (ws + WS_BOUND);

    convert_kernel<<<CVT_BLOCKS + W1T_BLOCKS + W2T_BLOCKS + 1, 256, 0, stream>>>(
        X, W1, W2, Xh, W1T, W2T, bnd);
    gemm1_kernel<<<(M_ROWS/64)*(DF/64), 256, 0, stream>>>(Xh, W1T, b1, Hh);
    gemm2_kernel<<<M_ROWS/32, 256, 0, stream>>>(Hh, W2T, b2, out_mean, out_var, out_wts);
    scan_kernel<<<BATCH*NMIX, 512, 0, stream>>>(initm, out_mean, out_var, bnd);
    attn_kernel<<<M_ROWS, 256, 0, stream>>>(out_mean, out_var, out_wts, bnd,
                                            out_attn, attnh);
    ctx_mfma_kernel<<<16*8*4, 256, 0, stream>>>(attnh, ctx, bnd, out_ctx);
}